// Round 2
// baseline (233.536 us; speedup 1.0000x reference)
//
#include <hip/hip_runtime.h>
#include <hip/hip_bf16.h>

#define WIN   9
#define NB    8
#define LL    4096
#define CC    256
#define UU    256
#define NW    (LL - WIN + 1)   // 4088
#define MROWS (NB * LL)        // 32768

__device__ __forceinline__ float bf16_to_f(unsigned short u) {
    return __uint_as_float(((unsigned int)u) << 16);
}

__device__ __forceinline__ float fast_tanh(float x) {
    // tanh(x) = 1 - 2/(exp(2x)+1); exp(inf)->inf -> rcp->0 -> 1 ; exp(-inf)->0 -> -1
    float e = __expf(2.0f * x);
    return 1.0f - 2.0f * __builtin_amdgcn_rcpf(e + 1.0f);
}

// ---------------- Kernel A: K = X@W_key, Q = X@W_qry (fp32 in, bf16 out) -----
// X: [MROWS, 256], W: [256,256], out: [MROWS, 256] bf16
// 64x64 tile, BK=16, 256 threads, each thread 4x4 microtile.
__global__ __launch_bounds__(256) void gemm_xw_bf16(
    const float* __restrict__ X,
    const float* __restrict__ Wk,
    const float* __restrict__ Wq,
    __hip_bfloat16* __restrict__ Kout,
    __hip_bfloat16* __restrict__ Qout)
{
    const float* W = (blockIdx.z == 0) ? Wk : Wq;
    __hip_bfloat16* O = (blockIdx.z == 0) ? Kout : Qout;

    const int m0 = blockIdx.y * 64;
    const int n0 = blockIdx.x * 64;

    __shared__ float As[16][64];   // [k][m]
    __shared__ float Bs[16][64];   // [k][n]

    const int tid = threadIdx.x;
    const int ty  = tid >> 4;      // 0..15 row group
    const int tx  = tid & 15;      // 0..15 col group

    float acc[4][4] = {};

    for (int k0 = 0; k0 < CC; k0 += 16) {
        // A tile: rows m0..m0+63, cols k0..k0+15  (store transposed [k][m])
        {
            int r = tid >> 2;            // 0..63
            int q = (tid & 3) * 4;       // 0,4,8,12
            float4 a = *reinterpret_cast<const float4*>(&X[(size_t)(m0 + r) * CC + k0 + q]);
            As[q + 0][r] = a.x;
            As[q + 1][r] = a.y;
            As[q + 2][r] = a.z;
            As[q + 3][r] = a.w;
        }
        // B tile: rows k0..k0+15, cols n0..n0+63
        {
            int r = tid >> 4;            // 0..15
            int c = (tid & 15) * 4;      // 0..60
            float4 bv = *reinterpret_cast<const float4*>(&W[(size_t)(k0 + r) * UU + n0 + c]);
            *reinterpret_cast<float4*>(&Bs[r][c]) = bv;
        }
        __syncthreads();
        #pragma unroll
        for (int kk = 0; kk < 16; ++kk) {
            float4 av = *reinterpret_cast<const float4*>(&As[kk][ty * 4]);
            float4 bv = *reinterpret_cast<const float4*>(&Bs[kk][tx * 4]);
            float a[4] = {av.x, av.y, av.z, av.w};
            float b[4] = {bv.x, bv.y, bv.z, bv.w};
            #pragma unroll
            for (int i = 0; i < 4; ++i)
                #pragma unroll
                for (int j = 0; j < 4; ++j)
                    acc[i][j] = fmaf(a[i], b[j], acc[i][j]);
        }
        __syncthreads();
    }

    #pragma unroll
    for (int i = 0; i < 4; ++i) {
        int m = m0 + ty * 4 + i;
        int n = n0 + tx * 4;
        __hip_bfloat16 tmp[4];
        #pragma unroll
        for (int j = 0; j < 4; ++j) tmp[j] = __float2bfloat16(acc[i][j]);
        *reinterpret_cast<ushort4*>(&O[(size_t)m * UU + n]) =
            *reinterpret_cast<const ushort4*>(tmp);
    }
}

// ---------------- Kernel B: score -> softmax -> weighted window sum ----------
// One wave per (n,w). Lane l owns u/c = 4l..4l+3.
__global__ __launch_bounds__(256) void attn_smooth(
    const float* __restrict__ X,
    const __hip_bfloat16* __restrict__ Kb,
    const __hip_bfloat16* __restrict__ Qb,
    const float* __restrict__ v,
    const float* __restrict__ b,
    float* __restrict__ out)
{
    const int wave = threadIdx.x >> 6;
    const int lane = threadIdx.x & 63;
    const int item = blockIdx.x * 4 + wave;   // < 8*4088 = 32704 exactly
    const int n = item / NW;
    const int w = item % NW;
    const int u0 = lane * 4;

    const size_t rowbase = (size_t)(n * LL + w);

    float4 bv = *reinterpret_cast<const float4*>(&b[u0]);
    float4 vv = *reinterpret_cast<const float4*>(&v[u0]);

    ushort4 qu = *reinterpret_cast<const ushort4*>(&Qb[(rowbase + WIN / 2) * UU + u0]);
    float qb0 = bf16_to_f(qu.x) + bv.x;
    float qb1 = bf16_to_f(qu.y) + bv.y;
    float qb2 = bf16_to_f(qu.z) + bv.z;
    float qb3 = bf16_to_f(qu.w) + bv.w;

    float score[WIN];
    #pragma unroll
    for (int s = 0; s < WIN; ++s) {
        ushort4 ku = *reinterpret_cast<const ushort4*>(&Kb[(rowbase + s) * UU + u0]);
        float p;
        p  = vv.x * fast_tanh(qb0 + bf16_to_f(ku.x));
        p += vv.y * fast_tanh(qb1 + bf16_to_f(ku.y));
        p += vv.z * fast_tanh(qb2 + bf16_to_f(ku.z));
        p += vv.w * fast_tanh(qb3 + bf16_to_f(ku.w));
        #pragma unroll
        for (int off = 32; off; off >>= 1) p += __shfl_xor(p, off);
        score[s] = p;
    }

    // softmax over WIN (all lanes redundantly)
    float m = score[0];
    #pragma unroll
    for (int s = 1; s < WIN; ++s) m = fmaxf(m, score[s]);
    float e[WIN];
    float sum = 0.0f;
    #pragma unroll
    for (int s = 0; s < WIN; ++s) { e[s] = __expf(score[s] - m); sum += e[s]; }
    float inv = 1.0f / sum;

    float4 acc = {0.0f, 0.0f, 0.0f, 0.0f};
    #pragma unroll
    for (int s = 0; s < WIN; ++s) {
        float ws = e[s] * inv;
        float4 xv = *reinterpret_cast<const float4*>(&X[(rowbase + s) * CC + u0]);
        acc.x = fmaf(ws, xv.x, acc.x);
        acc.y = fmaf(ws, xv.y, acc.y);
        acc.z = fmaf(ws, xv.z, acc.z);
        acc.w = fmaf(ws, xv.w, acc.w);
    }
    *reinterpret_cast<float4*>(&out[((size_t)n * NW + w) * CC + u0]) = acc;
}

extern "C" void kernel_launch(void* const* d_in, const int* in_sizes, int n_in,
                              void* d_out, int out_size, void* d_ws, size_t ws_size,
                              hipStream_t stream) {
    const float* x  = (const float*)d_in[0];
    const float* Wq = (const float*)d_in[1];
    const float* Wk = (const float*)d_in[2];
    const float* v  = (const float*)d_in[3];
    const float* b  = (const float*)d_in[4];
    float* out = (float*)d_out;

    __hip_bfloat16* Kbuf = (__hip_bfloat16*)d_ws;
    __hip_bfloat16* Qbuf = (__hip_bfloat16*)((char*)d_ws + (size_t)MROWS * UU * sizeof(__hip_bfloat16));

    dim3 gA(UU / 64, MROWS / 64, 2);           // (4, 512, 2)
    gemm_xw_bf16<<<gA, 256, 0, stream>>>(x, Wk, Wq, Kbuf, Qbuf);

    attn_smooth<<<(NB * NW) / 4, 256, 0, stream>>>(x, Kbuf, Qbuf, v, b, out);
}

// Round 3
// 151.093 us; speedup vs baseline: 1.5456x; 1.5456x over previous
//
#include <hip/hip_runtime.h>
#include <hip/hip_bf16.h>

#define WIN   9
#define NB    8
#define LL    4096
#define CC    256
#define UU    256
#define NW    (LL - WIN + 1)   // 4088
#define MROWS (NB * LL)        // 32768

typedef unsigned short ushort;
typedef __attribute__((ext_vector_type(8))) unsigned short ushort8v;
typedef __attribute__((ext_vector_type(4))) unsigned short ushort4v;
typedef __attribute__((ext_vector_type(8))) short short8v;
typedef __attribute__((ext_vector_type(4))) float f32x4;

__device__ __forceinline__ float bf16_to_f(ushort u) {
    return __uint_as_float(((unsigned int)u) << 16);
}
__device__ __forceinline__ ushort f2bf(float f) {
    __hip_bfloat16 h = __float2bfloat16(f);
    return *reinterpret_cast<ushort*>(&h);
}
__device__ __forceinline__ float fast_tanh(float x) {
    float e = __expf(2.0f * x);
    return 1.0f - 2.0f * __builtin_amdgcn_rcpf(e + 1.0f);
}

// ---------------- P1: X fp32 -> bf16 ----------------------------------------
__global__ __launch_bounds__(256) void cvt_x(const float* __restrict__ X,
                                             ushort* __restrict__ Xb) {
    size_t i = ((size_t)blockIdx.x * 256 + threadIdx.x) * 8;
    float4 v0 = *reinterpret_cast<const float4*>(X + i);
    float4 v1 = *reinterpret_cast<const float4*>(X + i + 4);
    ushort8v o;
    o[0] = f2bf(v0.x); o[1] = f2bf(v0.y); o[2] = f2bf(v0.z); o[3] = f2bf(v0.w);
    o[4] = f2bf(v1.x); o[5] = f2bf(v1.y); o[6] = f2bf(v1.z); o[7] = f2bf(v1.w);
    *reinterpret_cast<ushort8v*>(Xb + i) = o;
}

// ---------------- P2: W [c][u] fp32 -> WT [u][c] bf16 ------------------------
__global__ __launch_bounds__(256) void transpose_w(const float* __restrict__ Wk,
                                                   const float* __restrict__ Wq,
                                                   ushort* __restrict__ WkT,
                                                   ushort* __restrict__ WqT) {
    const float* W = blockIdx.z ? Wq : Wk;
    ushort* O = blockIdx.z ? WqT : WkT;
    __shared__ float t[32][33];
    int c0 = blockIdx.x * 32, u0 = blockIdx.y * 32;
    int tr = threadIdx.x >> 3, tc = (threadIdx.x & 7) * 4;
    float4 v = *reinterpret_cast<const float4*>(&W[(size_t)(c0 + tr) * UU + u0 + tc]);
    t[tr][tc + 0] = v.x; t[tr][tc + 1] = v.y; t[tr][tc + 2] = v.z; t[tr][tc + 3] = v.w;
    __syncthreads();
    ushort4v o;
    #pragma unroll
    for (int i = 0; i < 4; ++i) o[i] = f2bf(t[tc + i][tr]);
    *reinterpret_cast<ushort4v*>(&O[(size_t)(u0 + tr) * CC + c0 + tc]) = o;
}

// ---------------- Kernel A: MFMA GEMM  K/Q = Xb @ W --------------------------
// Tile 128(M) x 64(N), BK=32, 256 threads = 4 waves (2x2), 16x16x32 bf16 MFMA.
// LDS padded to stride 40 bf16 (80 B) -> only 2-way bank aliasing on b128 reads.
__global__ __launch_bounds__(256) void gemm_mfma(const ushort* __restrict__ Xb,
                                                 const ushort* __restrict__ WkT,
                                                 const ushort* __restrict__ WqT,
                                                 ushort* __restrict__ Kout,
                                                 ushort* __restrict__ Qout) {
    const int xb = blockIdx.x;                  // 0..7: 0-3 -> Wk, 4-7 -> Wq
    const ushort* WT = (xb < 4) ? WkT : WqT;
    ushort* Out = (xb < 4) ? Kout : Qout;
    const int nbase = (xb & 3) * 64;
    const int m0 = blockIdx.y * 128;

    __shared__ ushort As[128 * 40];
    __shared__ ushort Bs[64 * 40];

    const int tid = threadIdx.x;
    const int wid = tid >> 6, lane = tid & 63;
    const int wr = wid >> 1, wc = wid & 1;
    const int lrow = lane & 15, lk = (lane >> 4) * 8;

    f32x4 acc[4][2] = {};

    // staging addresses
    const int srow = tid >> 1, shalf = tid & 1;          // A: 128 rows x 2 halves
    const ushort* aSrc = Xb + (size_t)(m0 + srow) * CC + shalf * 16;
    ushort* aDst = &As[srow * 40 + shalf * 16];
    const int bu = tid >> 2, bk = (tid & 3) * 8;         // B: 64 rows x 4 chunks
    const ushort* bSrc = WT + (size_t)(nbase + bu) * CC + bk;
    ushort* bDst = &Bs[bu * 40 + bk];

    for (int k0 = 0; k0 < CC; k0 += 32) {
        ushort8v a0 = *reinterpret_cast<const ushort8v*>(aSrc + k0);
        ushort8v a1 = *reinterpret_cast<const ushort8v*>(aSrc + k0 + 8);
        ushort8v b0 = *reinterpret_cast<const ushort8v*>(bSrc + k0);
        *reinterpret_cast<ushort8v*>(aDst) = a0;
        *reinterpret_cast<ushort8v*>(aDst + 8) = a1;
        *reinterpret_cast<ushort8v*>(bDst) = b0;
        __syncthreads();

        short8v af[4], bf[2];
        #pragma unroll
        for (int m = 0; m < 4; ++m)
            af[m] = *reinterpret_cast<const short8v*>(&As[(wr * 64 + m * 16 + lrow) * 40 + lk]);
        #pragma unroll
        for (int n = 0; n < 2; ++n)
            bf[n] = *reinterpret_cast<const short8v*>(&Bs[(wc * 32 + n * 16 + lrow) * 40 + lk]);
        #pragma unroll
        for (int m = 0; m < 4; ++m)
            #pragma unroll
            for (int n = 0; n < 2; ++n)
                acc[m][n] = __builtin_amdgcn_mfma_f32_16x16x32_bf16(af[m], bf[n], acc[m][n], 0, 0, 0);
        __syncthreads();
    }

    // epilogue: C[row = (lane>>4)*4 + j, col = lane&15] per fragment
    const int orow = m0 + wr * 64 + (lane >> 4) * 4;
    const int ocol = nbase + wc * 32 + lrow;
    #pragma unroll
    for (int m = 0; m < 4; ++m)
        #pragma unroll
        for (int n = 0; n < 2; ++n)
            #pragma unroll
            for (int j = 0; j < 4; ++j)
                Out[(size_t)(orow + m * 16 + j) * UU + ocol + n * 16] = f2bf(acc[m][n][j]);
}

// ---------------- Kernel B: score -> softmax -> weighted window sum ----------
// One wave per (n,w). Lane l owns u/c = 4l..4l+3. XCD-contiguous item remap.
__global__ __launch_bounds__(256) void attn_smooth(
    const float* __restrict__ X,
    const ushort* __restrict__ Kb,
    const ushort* __restrict__ Qb,
    const float* __restrict__ v,
    const float* __restrict__ b,
    float* __restrict__ out) {
    const int wave = threadIdx.x >> 6;
    const int lane = threadIdx.x & 63;
    // bijective remap: XCD j gets contiguous block range [j*1022, (j+1)*1022)
    // = exactly batch n=j -> sliding-window rows stay hot in that XCD's L2.
    const int bid = blockIdx.x;
    const int nb = (bid & 7) * 1022 + (bid >> 3);
    const int item = nb * 4 + wave;           // < 8*4088 = 32704 exactly
    const int n = item / NW;
    const int w = item % NW;
    const int u0 = lane * 4;

    const size_t rowbase = (size_t)(n * LL + w);

    float4 bv = *reinterpret_cast<const float4*>(&b[u0]);
    float4 vv = *reinterpret_cast<const float4*>(&v[u0]);

    ushort4 qu = *reinterpret_cast<const ushort4*>(&Qb[(rowbase + WIN / 2) * UU + u0]);
    float qb0 = bf16_to_f(qu.x) + bv.x;
    float qb1 = bf16_to_f(qu.y) + bv.y;
    float qb2 = bf16_to_f(qu.z) + bv.z;
    float qb3 = bf16_to_f(qu.w) + bv.w;

    // all 9 partials first (ILP for the quarter-rate exp pipe) ...
    float p[WIN];
    #pragma unroll
    for (int s = 0; s < WIN; ++s) {
        ushort4 ku = *reinterpret_cast<const ushort4*>(&Kb[(rowbase + s) * UU + u0]);
        float t;
        t  = vv.x * fast_tanh(qb0 + bf16_to_f(ku.x));
        t += vv.y * fast_tanh(qb1 + bf16_to_f(ku.y));
        t += vv.z * fast_tanh(qb2 + bf16_to_f(ku.z));
        t += vv.w * fast_tanh(qb3 + bf16_to_f(ku.w));
        p[s] = t;
    }
    // ... then 6 butterfly stages, 9-wide ILP each
    #pragma unroll
    for (int off = 32; off; off >>= 1)
        #pragma unroll
        for (int s = 0; s < WIN; ++s)
            p[s] += __shfl_xor(p[s], off);

    float m = p[0];
    #pragma unroll
    for (int s = 1; s < WIN; ++s) m = fmaxf(m, p[s]);
    float e[WIN];
    float sum = 0.0f;
    #pragma unroll
    for (int s = 0; s < WIN; ++s) { e[s] = __expf(p[s] - m); sum += e[s]; }
    float inv = 1.0f / sum;

    float4 acc = {0.0f, 0.0f, 0.0f, 0.0f};
    #pragma unroll
    for (int s = 0; s < WIN; ++s) {
        float ws = e[s] * inv;
        float4 xv = *reinterpret_cast<const float4*>(&X[(rowbase + s) * CC + u0]);
        acc.x = fmaf(ws, xv.x, acc.x);
        acc.y = fmaf(ws, xv.y, acc.y);
        acc.z = fmaf(ws, xv.z, acc.z);
        acc.w = fmaf(ws, xv.w, acc.w);
    }
    *reinterpret_cast<float4*>(&out[((size_t)n * NW + w) * CC + u0]) = acc;
}

extern "C" void kernel_launch(void* const* d_in, const int* in_sizes, int n_in,
                              void* d_out, int out_size, void* d_ws, size_t ws_size,
                              hipStream_t stream) {
    const float* x  = (const float*)d_in[0];
    const float* Wq = (const float*)d_in[1];
    const float* Wk = (const float*)d_in[2];
    const float* v  = (const float*)d_in[3];
    const float* b  = (const float*)d_in[4];
    float* out = (float*)d_out;

    const size_t MU = (size_t)MROWS * UU;      // 8.39M elems
    ushort* Kbuf = (ushort*)d_ws;
    ushort* Qbuf = Kbuf + MU;
    ushort* Xb   = Qbuf + MU;
    ushort* WkT  = Xb + MU;
    ushort* WqT  = WkT + (size_t)CC * UU;

    cvt_x<<<MROWS * CC / (256 * 8), 256, 0, stream>>>(x, Xb);
    transpose_w<<<dim3(8, 8, 2), 256, 0, stream>>>(Wk, Wq, WkT, WqT);
    gemm_mfma<<<dim3(8, MROWS / 128), 256, 0, stream>>>(Xb, WkT, WqT, Kbuf, Qbuf);
    attn_smooth<<<(NB * NW) / 4, 256, 0, stream>>>(x, Kbuf, Qbuf, v, b, out);
}